// Round 8
// baseline (554.450 us; speedup 1.0000x reference)
//
#include <hip/hip_runtime.h>

#define BIGF 1e8f
static constexpr int NSEQ = 512;
static constexpr int NB = 32;

// lane l <- lane (l-1)&63 : DPP wavefront rotate-right-by-1 (gfx9 ctrl 0x13C).
// Must execute at full exec (disabled source lane would yield old=0).
__device__ __forceinline__ float rotup1(float v) {
  return __int_as_float(__builtin_amdgcn_update_dpp(
      0, __float_as_int(v), 0x13C, 0xf, 0xf, false));
}
// Wave-uniform read of lane `idx` — no memory, no waitcnt (SGPR result).
__device__ __forceinline__ float rlane(float v, int idx) {
  return __int_as_float(__builtin_amdgcn_readlane(__float_as_int(v), idx));
}

#define RL4(dst, src, idx)                                                     \
  dst.x = rlane(src.x, idx); dst.y = rlane(src.y, idx);                        \
  dst.z = rlane(src.z, idx); dst.w = rlane(src.w, idx);

// R8: 4 independent DP problems per wave (latency-chain overlap; R7 showed
// 79% chain stall at 1 problem/wave). 24 waves x 4 problems = 96.
// Per problem: R7-verified rotate-operand machinery (absmax 0).
// Band geometry (i, bot, top, act) identical across problems -> shared.
__global__ __launch_bounds__(64) void softdtw_band_kernel(
    const float* __restrict__ x, const float* __restrict__ y,
    float* __restrict__ ws)
{
  const int l = threadIdx.x;
  const float K1 = 0.721347520444482f;  // 1/(gamma*ln2), gamma=2
  const float K2 = 1.386294361119891f;  // gamma*ln2

#define PROBS(X) X(0) X(1) X(2) X(3)

#define DECL(p)                                                                \
  const int k_##p = blockIdx.x * 4 + p;                                        \
  const int batch_##p = k_##p & (NB - 1);                                      \
  const int type_##p = k_##p >> 5;                                             \
  const float4* Aq_##p = (const float4*)((type_##p == 2 ? y : x) +             \
                                         (size_t)batch_##p * NSEQ * 4);        \
  const float4* Bq_##p = (const float4*)((type_##p == 1 ? x : y) +             \
                                         (size_t)batch_##p * NSEQ * 4);        \
  float4 av_##p = Aq_##p[l];                                                   \
  float4 bseed_##p = Bq_##p[l];                                                \
  float4 w1a_##p = Aq_##p[64 + l];                                             \
  float4 w1b_##p = Bq_##p[51 + l];                                             \
  float4 w2a_##p = w1a_##p, w2b_##p = w1b_##p;                                 \
  float4 bv_##p;                                                               \
  RL4(bv_##p, bseed_##p, 0)                                                    \
  float r1_##p, upp_##p = BIGF;                                                \
  {                                                                            \
    float e0 = av_##p.x - bv_##p.x, e1 = av_##p.y - bv_##p.y,                  \
          e2 = av_##p.z - bv_##p.z, e3 = av_##p.w - bv_##p.w;                  \
    float dv00 = (e0 * e0 + e1 * e1) + (e2 * e2 + e3 * e3);                    \
    r1_##p = (l == 0) ? dv00 : BIGF;                                           \
  }
  PROBS(DECL)
#undef DECL

  int i = l;  // shared row index; invariant i = ilo + ((l-ilo)&63)

// Verified per-problem step core (R5/R6/R7). bot/top/act from enclosing scope.
#define STEP1(p, BJ, AJ)                                                       \
  {                                                                            \
    float rbx_ = rotup1(bv_##p.x);                                             \
    float rby_ = rotup1(bv_##p.y);                                             \
    float rbz_ = rotup1(bv_##p.z);                                             \
    float rbw_ = rotup1(bv_##p.w);                                             \
    float up = rotup1(r1_##p);                                                 \
    bv_##p.x = bot ? (BJ).x : rbx_;                                            \
    bv_##p.y = bot ? (BJ).y : rby_;                                            \
    bv_##p.z = bot ? (BJ).z : rbz_;                                            \
    bv_##p.w = bot ? (BJ).w : rbw_;                                            \
    av_##p.x = top ? (AJ).x : av_##p.x;                                        \
    av_##p.y = top ? (AJ).y : av_##p.y;                                        \
    av_##p.z = top ? (AJ).z : av_##p.z;                                        \
    av_##p.w = top ? (AJ).w : av_##p.w;                                        \
    float ddx = av_##p.x - bv_##p.x, ddy = av_##p.y - bv_##p.y,                \
          ddz = av_##p.z - bv_##p.z, ddw = av_##p.w - bv_##p.w;                \
    float dvv = ddx * ddx;                                                     \
    dvv = __builtin_fmaf(ddy, ddy, dvv);                                       \
    dvv = __builtin_fmaf(ddz, ddz, dvv);                                       \
    dvv = __builtin_fmaf(ddw, ddw, dvv);                                       \
    float left = r1_##p;                                                       \
    float dg = upp_##p;                                                        \
    float mn = fminf(fminf(up, left), dg);                                     \
    float mk = mn * K1;                                                        \
    float ssum = __builtin_exp2f(__builtin_fmaf(-K1, up, mk))                  \
               + __builtin_exp2f(__builtin_fmaf(-K1, left, mk))                \
               + __builtin_exp2f(__builtin_fmaf(-K1, dg, mk));                 \
    float rr = __builtin_fmaf(-K2, __builtin_log2f(ssum), mn + dvv);           \
    r1_##p = act ? rr : BIGF;                                                  \
    upp_##p = up;                                                              \
  }

#define DO_STEP(ILO, IHI, BJM, AJM)                                            \
  {                                                                            \
    const int ilo_ = (ILO);                                                    \
    const int ihi_ = (IHI);                                                    \
    i += (i < ilo_) ? 64 : 0;                                                  \
    const bool bot = (i == ilo_);                                              \
    const bool top = (i == ilo_ + 63);                                         \
    const bool act = (i <= ihi_);                                              \
    STEP1(0, BJM(0), AJM(0))                                                   \
    STEP1(1, BJM(1), AJM(1))                                                   \
    STEP1(2, BJM(2), AJM(2))                                                   \
    STEP1(3, BJM(3), AJM(3))                                                   \
  }

  // ---- Phase 1: d = 1..50 (ilo=0, ihi=d, binj=b[d], ainj=a[63] no-op) ----
#define D1(p) float4 aP1_##p; RL4(aP1_##p, av_##p, 63)
  PROBS(D1)
#undef D1
#define AP1M(p) aP1_##p
#define BJ1M(p) bj_##p
  #pragma unroll 2
  for (int d = 1; d <= 50; ++d) {
#define D2(p) float4 bj_##p; RL4(bj_##p, bseed_##p, d)
    PROBS(D2)
#undef D2
    DO_STEP(0, d, BJ1M, AP1M)
  }
#define D3(p) float4 bprev_##p; RL4(bprev_##p, bseed_##p, 50)
  PROBS(D3)
#undef D3

  // ---- Phase 2: 7 epochs x 64 two-step macros (d = 51..946) ----
#define BPREVM(p) bprev_##p
#define BNEWM(p) bnew_##p
#define ANEWM(p) anew_##p
#define EPOCH(E, CA, CB, NA, NB_)                                              \
  {                                                                            \
    const int ia_ = min(NSEQ - 1, 64 + 64 * ((E) + 1) + l);                    \
    const int ib_ = min(NSEQ - 1, 51 + 64 * ((E) + 1) + l);                    \
    NA(0) = Aq_0[ia_]; NB_(0) = Bq_0[ib_];                                     \
    NA(1) = Aq_1[ia_]; NB_(1) = Bq_1[ib_];                                     \
    NA(2) = Aq_2[ia_]; NB_(2) = Bq_2[ib_];                                     \
    NA(3) = Aq_3[ia_]; NB_(3) = Bq_3[ib_];                                     \
    _Pragma("unroll 2")                                                        \
    for (int m2 = 0; m2 < 64; ++m2) {                                          \
      const int m = 64 * (E) + m2;                                             \
      float4 bnew_0, bnew_1, bnew_2, bnew_3;                                   \
      float4 anew_0, anew_1, anew_2, anew_3;                                   \
      RL4(bnew_0, CB(0), m2) RL4(anew_0, CA(0), m2)                            \
      RL4(bnew_1, CB(1), m2) RL4(anew_1, CA(1), m2)                            \
      RL4(bnew_2, CB(2), m2) RL4(anew_2, CA(2), m2)                            \
      RL4(bnew_3, CB(3), m2) RL4(anew_3, CA(3), m2)                            \
      DO_STEP(m + 1, m + 50, BPREVM, ANEWM)                                    \
      DO_STEP(m + 1, m + 51, BNEWM, ANEWM)                                     \
      bprev_0 = bnew_0; bprev_1 = bnew_1;                                      \
      bprev_2 = bnew_2; bprev_3 = bnew_3;                                      \
    }                                                                          \
  }
#define W1A(p) w1a_##p
#define W1B(p) w1b_##p
#define W2A(p) w2a_##p
#define W2B(p) w2b_##p
  EPOCH(0, W1A, W1B, W2A, W2B)
  EPOCH(1, W2A, W2B, W1A, W1B)
  EPOCH(2, W1A, W1B, W2A, W2B)
  EPOCH(3, W2A, W2B, W1A, W1B)
  EPOCH(4, W1A, W1B, W2A, W2B)
  EPOCH(5, W2A, W2B, W1A, W1B)
  EPOCH(6, W1A, W1B, W2A, W2B)  // refills w2 = epoch-7 windows (b base 499)
#undef EPOCH

  // Tail constants: a[511] = w1a(idx 63, base 448); b[511] = w2b(idx 12, base 499).
#define D4(p)                                                                  \
  float4 a3_##p;   RL4(a3_##p, w1a_##p, 63)                                    \
  float4 b511_##p; RL4(b511_##p, w2b_##p, 12)
  PROBS(D4)
#undef D4
#define A3M(p) a3_##p
#define B511M(p) b511_##p

  // ---- Phase 2t: macros m = 448..460 (d = 947..972), a-injection = a[511] ----
  #pragma unroll 2
  for (int m = 448; m <= 460; ++m) {
    float4 bnew_0, bnew_1, bnew_2, bnew_3;
    RL4(bnew_0, w2b_0, m - 448)
    RL4(bnew_1, w2b_1, m - 448)
    RL4(bnew_2, w2b_2, m - 448)
    RL4(bnew_3, w2b_3, m - 448)
    DO_STEP(m + 1, m + 50, BPREVM, A3M)
    DO_STEP(m + 1, m + 51, BNEWM, A3M)
    bprev_0 = bnew_0; bprev_1 = bnew_1;
    bprev_2 = bnew_2; bprev_3 = bnew_3;
  }

  // ---- Phase 3: d = 973..1022 (ilo = d-511, ihi = 511, const injections) ----
  #pragma unroll 2
  for (int d = 973; d <= 1022; ++d) {
    DO_STEP(d - 511, NSEQ - 1, B511M, A3M)
  }

  // R[511,511]: row 511 on lane 63.
  if (l == 63) {
    ws[k_0] = r1_0;
    ws[k_1] = r1_1;
    ws[k_2] = r1_2;
    ws[k_3] = r1_3;
  }
}

__global__ void softdtw_combine_kernel(const float* __restrict__ ws,
                                       float* __restrict__ out) {
  int b = threadIdx.x;
  if (b < NB) out[b] = ws[b] - 0.5f * (ws[NB + b] + ws[2 * NB + b]);
}

extern "C" void kernel_launch(void* const* d_in, const int* in_sizes, int n_in,
                              void* d_out, int out_size, void* d_ws, size_t ws_size,
                              hipStream_t stream) {
  const float* x = (const float*)d_in[0];
  const float* y = (const float*)d_in[1];
  float* ws = (float*)d_ws;
  float* out = (float*)d_out;
  softdtw_band_kernel<<<24, 64, 0, stream>>>(x, y, ws);
  softdtw_combine_kernel<<<1, 64, 0, stream>>>(ws, out);
}

// Round 9
// 141.823 us; speedup vs baseline: 3.9094x; 3.9094x over previous
//
#include <hip/hip_runtime.h>

static constexpr int NSEQ = 512;
static constexpr int NB = 32;
#define SNEG (-(1 << 30))   // scale of "BIG" (E=0) lanes; never wins max3

// lane l <- lane (l-1)&63 : DPP wavefront rotate-right-by-1 (gfx9 ctrl 0x13C).
// Must execute at full exec (disabled source lane would yield old=0).
__device__ __forceinline__ float rotup1f(float v) {
  return __int_as_float(__builtin_amdgcn_update_dpp(
      0, __float_as_int(v), 0x13C, 0xf, 0xf, false));
}
__device__ __forceinline__ int rotup1i(int v) {
  return __builtin_amdgcn_update_dpp(0, v, 0x13C, 0xf, 0xf, false);
}
__device__ __forceinline__ float rlane(float v, int idx) {
  return __int_as_float(__builtin_amdgcn_readlane(__float_as_int(v), idx));
}
#define RL4(dst, src, idx)                                                     \
  dst.x = rlane(src.x, idx); dst.y = rlane(src.y, idx);                        \
  dst.z = rlane(src.z, idx); dst.w = rlane(src.w, idx);

// R9: exp/log-free recurrence. Represent R as E = m * 2^s  (E = 2^{-K1*R},
// m in [1,2), s int). softDTW step:  E_new = 2^{-K1*D} * (Eu + El + Ed).
// Alignment to sref=max3(s); per-step renorm via exponent bit-extraction
// (pre in [1,12] for active lanes — every active cell has >=1 finite
// max-aligned neighbor). Inactive/BIG lanes: (m=0, s=SNEG).
// Band/rotate/injection machinery identical to the verified R5/R7 scheme.
__global__ __launch_bounds__(64) void softdtw_band_kernel(
    const float* __restrict__ x, const float* __restrict__ y,
    float* __restrict__ ws)
{
  const int k = blockIdx.x;
  const int batch = k & (NB - 1);
  const int type = k >> 5;
  const float4* Aq = (const float4*)((type == 2 ? y : x) + (size_t)batch * NSEQ * 4);
  const float4* Bq = (const float4*)((type == 1 ? x : y) + (size_t)batch * NSEQ * 4);

  const int l = threadIdx.x;
  const float K1 = 0.721347520444482f;  // 1/(gamma*ln2), gamma=2
  const float K2 = 1.386294361119891f;  // gamma*ln2

  float4 av    = Aq[l];        // a[i], i=l
  float4 bseed = Bq[l];        // b[0..63] window for P1 injections
  float4 w1a   = Aq[64 + l];   // epoch-0 a-window: a[64..127]
  float4 w1b   = Bq[51 + l];   // epoch-0 b-window: b[51..114]
  float4 w2a = w1a, w2b = w1b;

  float4 bv; RL4(bv, bseed, 0)

  // Seed d=0: R[0,0] = D(0,0)  ->  E = 2^{-K1*dv00} on lane 0.
  float EM; int ES;
  float uppm = 0.0f; int upps = SNEG;   // diag init = BIG
  {
    float e0 = av.x - bv.x, e1 = av.y - bv.y, e2 = av.z - bv.z, e3 = av.w - bv.w;
    float dv00 = (e0 * e0 + e1 * e1) + (e2 * e2 + e3 * e3);
    float t = dv00 * (-K1);
    float fl = __builtin_floorf(t);
    float m0 = __builtin_exp2f(t - fl);   // [1,2)
    EM = (l == 0) ? m0 : 0.0f;
    ES = (l == 0) ? (int)fl : SNEG;
  }
  int i = l;  // row; invariant i = ilo + ((l-ilo)&63)

// E-space step core. BOT/ACT precomputed bools; BJ = uniform injected b[j].
// DPPs unconditional at full exec; selects are cndmask.
#define CORE(BOT, ACT, BJ)                                                     \
  {                                                                            \
    float rbx_ = rotup1f(bv.x);                                                \
    float rby_ = rotup1f(bv.y);                                                \
    float rbz_ = rotup1f(bv.z);                                                \
    float rbw_ = rotup1f(bv.w);                                                \
    float upm_ = rotup1f(EM);                                                  \
    int   ups_ = rotup1i(ES);                                                  \
    bv.x = (BOT) ? (BJ).x : rbx_;                                              \
    bv.y = (BOT) ? (BJ).y : rby_;                                              \
    bv.z = (BOT) ? (BJ).z : rbz_;                                              \
    bv.w = (BOT) ? (BJ).w : rbw_;                                              \
    float ddx = av.x - bv.x, ddy = av.y - bv.y,                                \
          ddz = av.z - bv.z, ddw = av.w - bv.w;                                \
    float dvv = ddx * ddx;                                                     \
    dvv = __builtin_fmaf(ddy, ddy, dvv);                                       \
    dvv = __builtin_fmaf(ddz, ddz, dvv);                                       \
    dvv = __builtin_fmaf(ddw, ddw, dvv);                                       \
    float t_  = dvv * (-K1);                                                   \
    float fl_ = __builtin_floorf(t_);                                          \
    float dm_ = __builtin_exp2f(t_ - fl_);  /* [1,2), off critical path */     \
    int   ti_ = (int)fl_;                                                      \
    int sref_ = max(max(ups_, ES), upps);                                      \
    float tu_ = __builtin_ldexpf(upm_, ups_ - sref_);                          \
    float tl_ = __builtin_ldexpf(EM,   ES   - sref_);                          \
    float td_ = __builtin_ldexpf(uppm, upps - sref_);                          \
    float pre_ = ((tu_ + tl_) + td_) * dm_;   /* in [1,12] for active */       \
    int pb_ = __float_as_int(pre_);                                            \
    int ee_ = (pb_ >> 23) - 127;                                               \
    float em_ = __int_as_float((pb_ & 0x007FFFFF) | 0x3F800000);               \
    int sn_ = (sref_ + ti_) + ee_;                                             \
    EM = (ACT) ? em_ : 0.0f;                                                   \
    ES = (ACT) ? sn_ : SNEG;                                                   \
    uppm = upm_; upps = ups_;                                                  \
  }

  // ---- P1: d = 1..50 (ilo=0, no jumps, bot = lane0 const, act = l<=d) ----
  {
    const bool bot = (l == 0);
    #pragma unroll 2
    for (int d = 1; d <= 50; ++d) {
      float4 bj; RL4(bj, bseed, d)
      const bool act = (l <= d);
      CORE(bot, act, bj)
    }
  }
  float4 bprev; RL4(bprev, bseed, 50)

// Two-step macro for d = 51+2m, 52+2m (ilo = m+1 both; jump on first step).
// av update once per macro (jumped lane inactive for 26 steps — grace ok).
#define MACRO(M, ANEWV, BPREVV, BNEWV)                                         \
  {                                                                            \
    i += (i < (M) + 1) ? 64 : 0;                                               \
    const bool bot  = (i == (M) + 1);                                          \
    const bool actA = (i <= (M) + 50);                                         \
    const bool actB = (i <= (M) + 51);                                         \
    const bool top  = (i == (M) + 64);                                         \
    av.x = top ? (ANEWV).x : av.x;                                             \
    av.y = top ? (ANEWV).y : av.y;                                             \
    av.z = top ? (ANEWV).z : av.z;                                             \
    av.w = top ? (ANEWV).w : av.w;                                             \
    CORE(bot, actA, BPREVV)                                                    \
    CORE(bot, actB, BNEWV)                                                     \
  }

  // ---- P2: 7 epochs x 64 macros (d = 51..946) ----
#define EPOCH(E, CA, CB, NA, NB_)                                              \
  {                                                                            \
    NA  = Aq[min(NSEQ - 1, 64 + 64 * ((E) + 1) + l)];                          \
    NB_ = Bq[min(NSEQ - 1, 51 + 64 * ((E) + 1) + l)];                          \
    _Pragma("unroll 2")                                                        \
    for (int m2 = 0; m2 < 64; ++m2) {                                          \
      const int m = 64 * (E) + m2;                                             \
      float4 bnew, anew;                                                       \
      RL4(bnew, CB, m2)                                                        \
      RL4(anew, CA, m2)                                                        \
      MACRO(m, anew, bprev, bnew)                                              \
      bprev = bnew;                                                            \
    }                                                                          \
  }
  EPOCH(0, w1a, w1b, w2a, w2b)
  EPOCH(1, w2a, w2b, w1a, w1b)
  EPOCH(2, w1a, w1b, w2a, w2b)
  EPOCH(3, w2a, w2b, w1a, w1b)
  EPOCH(4, w1a, w1b, w2a, w2b)
  EPOCH(5, w2a, w2b, w1a, w1b)
  EPOCH(6, w1a, w1b, w2a, w2b)   // leaves w2 = epoch-7 windows (b base 499)
#undef EPOCH

  // Tail constants: a[511] = w1a[63] (base 448); b[511] = w2b[12] (base 499).
  float4 a3;   RL4(a3, w1a, 63)
  float4 b511; RL4(b511, w2b, 12)

  // ---- P2t: macros m = 448..460 (d = 947..972), a-injection = a[511] ----
  #pragma unroll 2
  for (int m = 448; m <= 460; ++m) {
    float4 bnew; RL4(bnew, w2b, m - 448)
    MACRO(m, a3, bprev, bnew)
    bprev = bnew;
  }
#undef MACRO

  // ---- P3: d = 973..1022 (ilo = d-511, ihi = 511, const injections; the
  // per-step jumped lane lands in the top region, inactive through d=1022) ----
  #pragma unroll 2
  for (int d = 973; d <= 1022; ++d) {
    const int ilo_ = d - 511;
    i += (i < ilo_) ? 64 : 0;
    const bool bot = (i == ilo_);
    const bool act = (i <= NSEQ - 1);
    CORE(bot, act, b511)
  }
#undef CORE

  // R[511,511] on lane 63:  R = -K2 * (log2(m) + s).
  if (l == 63) {
    ws[k] = -K2 * (__builtin_log2f(EM) + (float)ES);
  }
}

__global__ void softdtw_combine_kernel(const float* __restrict__ ws,
                                       float* __restrict__ out) {
  int b = threadIdx.x;
  if (b < NB) out[b] = ws[b] - 0.5f * (ws[NB + b] + ws[2 * NB + b]);
}

extern "C" void kernel_launch(void* const* d_in, const int* in_sizes, int n_in,
                              void* d_out, int out_size, void* d_ws, size_t ws_size,
                              hipStream_t stream) {
  const float* x = (const float*)d_in[0];
  const float* y = (const float*)d_in[1];
  float* ws = (float*)d_ws;
  float* out = (float*)d_out;
  softdtw_band_kernel<<<3 * NB, 64, 0, stream>>>(x, y, ws);
  softdtw_combine_kernel<<<1, 64, 0, stream>>>(ws, out);
}

// Round 11
// 113.227 us; speedup vs baseline: 4.8968x; 1.2526x over previous
//
#include <hip/hip_runtime.h>

static constexpr int NSEQ = 512;
static constexpr int NB = 32;
#define SNEG (-(1 << 30))   // scale of "zero/BIG" lanes; never wins max3

// lane l <- lane (l-1)&63 : DPP wavefront rotate-right-by-1 (gfx9 ctrl 0x13C).
// Must execute at full exec (disabled source lane would yield old=0).
__device__ __forceinline__ float rotup1f(float v) {
  return __int_as_float(__builtin_amdgcn_update_dpp(
      0, __float_as_int(v), 0x13C, 0xf, 0xf, false));
}
__device__ __forceinline__ int rotup1i(int v) {
  return __builtin_amdgcn_update_dpp(0, v, 0x13C, 0xf, 0xf, false);
}
__device__ __forceinline__ float rlane(float v, int idx) {
  return __int_as_float(__builtin_amdgcn_readlane(__float_as_int(v), idx));
}
#define RL4(dst, src, idx)                                                     \
  dst.x = rlane(src.x, idx); dst.y = rlane(src.y, idx);                        \
  dst.z = rlane(src.z, idx); dst.w = rlane(src.w, idx);

// R11 = verified R9 + two low-risk diet items (bisect vs R10's failure):
//  (2') readlane-free injections: three per-lane epoch buffers
//       anext[l]=A[64+64E+l], bA[l]=B[50+64E+((l-1)&63)], bB[l]=B[51+64E+((l-1)&63)]
//       -> step-A inject bA (value b[50+m] at bot lane (m2+1)&63), step-B
//       inject bB (b[51+m]); same values R9 injected via readlane.
//  (4) dm = exp2(-K1*dvv) directly (no floor/frac/cvt); normal-range safe.
// Everything else identical to R9: per-step full renorm, step-A injection
// kept, P2t injects a[511] at top, P3 injects uniform b[511] at bot.
__global__ __launch_bounds__(64) void softdtw_band_kernel(
    const float* __restrict__ x, const float* __restrict__ y,
    float* __restrict__ ws)
{
  const int k = blockIdx.x;
  const int batch = k & (NB - 1);
  const int type = k >> 5;
  const float4* Aq = (const float4*)((type == 2 ? y : x) + (size_t)batch * NSEQ * 4);
  const float4* Bq = (const float4*)((type == 1 ? x : y) + (size_t)batch * NSEQ * 4);

  const int l = threadIdx.x;
  const float K1 = 0.721347520444482f;  // 1/(gamma*ln2), gamma=2
  const float K2 = 1.386294361119891f;  // gamma*ln2

  float4 av    = Aq[l];                    // a[i], i=l
  float4 bseed = Bq[l];                    // b-window for P1 injections
  float4 anc   = Aq[64 + l];               // epoch-0 anext
  float4 bac   = Bq[50 + ((l - 1) & 63)];  // epoch-0 step-A b-buffer
  float4 bbc   = Bq[51 + ((l - 1) & 63)];  // epoch-0 step-B b-buffer
  float4 ann = anc, ban = bac, bbn = bbc;  // alternate (double-buffer)

  float4 bv; RL4(bv, bseed, 0)

  // Seed d=0 (R9 split form): E = m0 * 2^fl, m0 in [1,2).
  float EM; int ES;
  float uppm = 0.0f; int upps = SNEG;
  {
    float e0 = av.x - bv.x, e1 = av.y - bv.y, e2 = av.z - bv.z, e3 = av.w - bv.w;
    float dv00 = (e0 * e0 + e1 * e1) + (e2 * e2 + e3 * e3);
    float t = dv00 * (-K1);
    float fl = __builtin_floorf(t);
    float m0 = __builtin_exp2f(t - fl);
    EM = (l == 0) ? m0 : 0.0f;
    ES = (l == 0) ? (int)fl : SNEG;
  }
  int i = l;  // row; invariant i = ilo + ((l-ilo)&63)

// E-space step (R9 CORE, full renorm every step; direct exp2 for dm).
#define CORE(BOT, ACT, BJ)                                                     \
  {                                                                            \
    float rbx_ = rotup1f(bv.x);                                                \
    float rby_ = rotup1f(bv.y);                                                \
    float rbz_ = rotup1f(bv.z);                                                \
    float rbw_ = rotup1f(bv.w);                                                \
    float upm_ = rotup1f(EM);                                                  \
    int   ups_ = rotup1i(ES);                                                  \
    bv.x = (BOT) ? (BJ).x : rbx_;                                              \
    bv.y = (BOT) ? (BJ).y : rby_;                                              \
    bv.z = (BOT) ? (BJ).z : rbz_;                                              \
    bv.w = (BOT) ? (BJ).w : rbw_;                                              \
    float ddx = av.x - bv.x, ddy = av.y - bv.y,                                \
          ddz = av.z - bv.z, ddw = av.w - bv.w;                                \
    float dvv = ddx * ddx;                                                     \
    dvv = __builtin_fmaf(ddy, ddy, dvv);                                       \
    dvv = __builtin_fmaf(ddz, ddz, dvv);                                       \
    dvv = __builtin_fmaf(ddw, ddw, dvv);                                       \
    float dm_ = __builtin_exp2f(dvv * (-K1));                                  \
    int sref_ = max(max(ups_, ES), upps);                                      \
    float pre_ = (__builtin_ldexpf(upm_, ups_ - sref_)                         \
                + __builtin_ldexpf(EM,   ES   - sref_)                         \
                + __builtin_ldexpf(uppm, upps - sref_)) * dm_;                 \
    int pb_ = __float_as_int(pre_);                                            \
    float em_ = __int_as_float((pb_ & 0x007FFFFF) | 0x3F800000);               \
    int sn_ = sref_ + ((pb_ >> 23) - 127);                                     \
    EM = (ACT) ? em_ : 0.0f;                                                   \
    ES = (ACT) ? sn_ : SNEG;                                                   \
    uppm = upm_; upps = ups_;                                                  \
  }

  // ---- P1: d = 1..50 (ilo=0, no jumps; inject b[d] at lane 0) ----
  {
    const bool bot = (l == 0);
    #pragma unroll 2
    for (int d = 1; d <= 50; ++d) {
      float4 bj; RL4(bj, bseed, d)
      const bool act = (l <= d);
      CORE(bot, act, bj)
    }
  }

// Two-step macro for d = 51+2m, 52+2m (ilo = m+1). Injections at bot from
// per-lane buffers BA (b[50+m]) and BB (b[51+m]); a[m+64] at top from ANC.
#define MACRO(MM, ANC, BA, BB)                                                 \
  {                                                                            \
    const int m_ = (MM);                                                       \
    i += (i < m_ + 1) ? 64 : 0;                                                \
    const bool bot  = (i == m_ + 1);                                           \
    const bool top  = (i == m_ + 64);                                          \
    const bool actA = (i <= m_ + 50);                                          \
    const bool actB = (i <= m_ + 51);                                          \
    av.x = top ? (ANC).x : av.x;                                               \
    av.y = top ? (ANC).y : av.y;                                               \
    av.z = top ? (ANC).z : av.z;                                               \
    av.w = top ? (ANC).w : av.w;                                               \
    CORE(bot, actA, BA)                                                        \
    CORE(bot, actB, BB)                                                        \
  }

  // ---- P2: 7 epochs x 64 macros (d = 51..946); refill next buffers early ----
#define EPOCH(E, CA, CBA, CBB, NA, NBA, NBB)                                   \
  {                                                                            \
    NA  = Aq[min(NSEQ - 1, 64 + 64 * ((E) + 1) + l)];                          \
    NBA = Bq[min(NSEQ - 1, 50 + 64 * ((E) + 1) + ((l - 1) & 63))];             \
    NBB = Bq[min(NSEQ - 1, 51 + 64 * ((E) + 1) + ((l - 1) & 63))];             \
    _Pragma("unroll 2")                                                        \
    for (int m2 = 0; m2 < 64; ++m2) {                                          \
      MACRO(64 * (E) + m2, CA, CBA, CBB)                                       \
    }                                                                          \
  }
  EPOCH(0, anc, bac, bbc, ann, ban, bbn)
  EPOCH(1, ann, ban, bbn, anc, bac, bbc)
  EPOCH(2, anc, bac, bbc, ann, ban, bbn)
  EPOCH(3, ann, ban, bbn, anc, bac, bbc)
  EPOCH(4, anc, bac, bbc, ann, ban, bbn)
  EPOCH(5, ann, ban, bbn, anc, bac, bbc)
  EPOCH(6, anc, bac, bbc, ann, ban, bbn)  // leaves epoch-7 buffers in ann/ban/bbn
#undef EPOCH

  // ---- P2t: macros m = 448..460 (d = 947..972). ann = a[511] everywhere
  // (tops' rows >= 512, inactive forever — same injected value as R9's a3). ----
  for (int m = 448; m <= 460; ++m) {
    MACRO(m, ann, ban, bbn)
  }
#undef MACRO

  // ---- P3: d = 973..1022 (ilo = d-511, ihi = 511; uniform b[511] at bot) ----
  float4 b511; RL4(b511, bbn, 13)   // bbn[13] = B[499+12] = b[511]
  #pragma unroll 2
  for (int d = 973; d <= 1022; ++d) {
    i += (i < d - 511) ? 64 : 0;
    const bool bot = (i == d - 511);
    const bool act = (i <= NSEQ - 1);
    CORE(bot, act, b511)
  }
#undef CORE

  // R[511,511] on lane 63:  R = -K2 * (log2(m) + s).
  if (l == 63) {
    ws[k] = -K2 * (__builtin_log2f(EM) + (float)ES);
  }
}

__global__ void softdtw_combine_kernel(const float* __restrict__ ws,
                                       float* __restrict__ out) {
  int b = threadIdx.x;
  if (b < NB) out[b] = ws[b] - 0.5f * (ws[NB + b] + ws[2 * NB + b]);
}

extern "C" void kernel_launch(void* const* d_in, const int* in_sizes, int n_in,
                              void* d_out, int out_size, void* d_ws, size_t ws_size,
                              hipStream_t stream) {
  const float* x = (const float*)d_in[0];
  const float* y = (const float*)d_in[1];
  float* ws = (float*)d_ws;
  float* out = (float*)d_out;
  softdtw_band_kernel<<<3 * NB, 64, 0, stream>>>(x, y, ws);
  softdtw_combine_kernel<<<1, 64, 0, stream>>>(ws, out);
}